// Round 1
// baseline (603.337 us; speedup 1.0000x reference)
//
#include <hip/hip_runtime.h>
#include <stdint.h>

typedef __attribute__((ext_vector_type(8))) short short8;
typedef __attribute__((ext_vector_type(4))) float f32x4;

#define DIM 768
#define H3 2304
#define SEQ 4096
#define NTOK 16384

__device__ __forceinline__ unsigned short f2bf(float f) {
  union { float f; uint32_t u; } c; c.f = f;
  uint32_t u = c.u;
  u += 0x7FFFu + ((u >> 16) & 1u);   // RNE; inputs are finite
  return (unsigned short)(u >> 16);
}

__device__ __forceinline__ void async_cp16(const void* g, void* l) {
  // global -> LDS direct, 16B per lane. LDS dest must be waveBase + lane*16 (it is).
  __builtin_amdgcn_global_load_lds(
      (__attribute__((address_space(1))) void*)(void*)g,
      (__attribute__((address_space(3))) void*)l, 16, 0, 0);
}

// NT GEMM core: C[128x128] tile = A[128xK] * B[128xK]^T, bf16 in, fp32 acc.
// 256 threads = 4 waves, each wave 64x64 (4x4 of 16x16x32 MFMA).
__device__ __forceinline__ void gemm_nt_core(
    const unsigned short* __restrict__ A, const unsigned short* __restrict__ B,
    int K, int ldA, int ldB, int rowA0, int rowB0,
    unsigned short* As, unsigned short* Bs, f32x4 acc[4][4])
{
  const int tid  = threadIdx.x;
  const int lane = tid & 63;
  const int wid  = tid >> 6;
  const int wm   = (wid & 1) << 6;
  const int wn   = (wid >> 1) << 6;

#pragma unroll
  for (int i = 0; i < 4; ++i)
#pragma unroll
    for (int j = 0; j < 4; ++j)
      acc[i][j] = (f32x4){0.f, 0.f, 0.f, 0.f};

  // staging: tile is 128 rows x 32 cols bf16 = 8KB = 512 chunks of 16B; 256 thr x 2
  const int c0 = tid, c1 = tid + 256;
  const int r0 = c0 >> 2, cc0 = (c0 & 3) << 3;
  const int r1 = c1 >> 2, cc1 = (c1 & 3) << 3;
  const unsigned short* ga0 = A + (size_t)(rowA0 + r0) * ldA + cc0;
  const unsigned short* ga1 = A + (size_t)(rowA0 + r1) * ldA + cc1;
  const unsigned short* gb0 = B + (size_t)(rowB0 + r0) * ldB + cc0;
  const unsigned short* gb1 = B + (size_t)(rowB0 + r1) * ldB + cc1;

  const int lr = lane & 15;          // row within 16-tile
  const int kq = (lane >> 4) << 3;   // k-offset (8 elems per lane-quad)

  for (int k0 = 0; k0 < K; k0 += 32) {
    async_cp16(ga0 + k0, As + c0 * 8);
    async_cp16(ga1 + k0, As + c1 * 8);
    async_cp16(gb0 + k0, Bs + c0 * 8);
    async_cp16(gb1 + k0, Bs + c1 * 8);
    __syncthreads();   // drains vmcnt -> LDS tiles ready

    short8 af[4], bfr[4];
#pragma unroll
    for (int i = 0; i < 4; ++i)
      af[i] = *(const short8*)(As + (wm + i * 16 + lr) * 32 + kq);
#pragma unroll
    for (int j = 0; j < 4; ++j)
      bfr[j] = *(const short8*)(Bs + (wn + j * 16 + lr) * 32 + kq);
#pragma unroll
    for (int i = 0; i < 4; ++i)
#pragma unroll
      for (int j = 0; j < 4; ++j)
        acc[i][j] = __builtin_amdgcn_mfma_f32_16x16x32_bf16(af[i], bfr[j], acc[i][j], 0, 0, 0);
    __syncthreads();   // all waves done reading LDS before restage
  }
}

// ---- kernel 0a: fp32 -> bf16 bulk convert (x) ----
__global__ __launch_bounds__(256) void k_cvt(const float* __restrict__ in,
                                             unsigned short* __restrict__ o) {
  int i = blockIdx.x * 256 + threadIdx.x;   // exact grid, no bounds needed
  float4 f = ((const float4*)in)[i];
  ushort4 u;
  u.x = f2bf(f.x); u.y = f2bf(f.y); u.z = f2bf(f.z); u.w = f2bf(f.w);
  ((ushort4*)o)[i] = u;
}

// ---- kernel 0b: W [768,2304] fp32 -> Wt [2304,768] bf16 (tiled transpose) ----
__global__ __launch_bounds__(256) void k_transpose(const float* __restrict__ W,
                                                   unsigned short* __restrict__ Wt) {
  __shared__ float tile[32][33];
  const int bc = blockIdx.x * 32;           // col block in W (2304)
  const int br = blockIdx.y * 32;           // row block in W (768)
  const int tx = threadIdx.x & 31, ty = threadIdx.x >> 5;
#pragma unroll
  for (int i = 0; i < 32; i += 8)
    tile[ty + i][tx] = W[(size_t)(br + ty + i) * H3 + bc + tx];
  __syncthreads();
#pragma unroll
  for (int i = 0; i < 32; i += 8)
    Wt[(size_t)(bc + ty + i) * DIM + br + tx] = f2bf(tile[tx][ty + i]);
}

// ---- kernel 1: qkv = x @ Wt^T + b ; writes q(bf16,*1/sqrt(H)), k(bf16), vT(bf16 transposed) ----
__global__ __launch_bounds__(256) void k_qkv(
    const unsigned short* __restrict__ xbf, const unsigned short* __restrict__ Wt,
    const float* __restrict__ bias,
    unsigned short* __restrict__ qb, unsigned short* __restrict__ kb,
    unsigned short* __restrict__ vT)
{
  __shared__ unsigned short As[128 * 32];
  __shared__ unsigned short Bs[128 * 32];
  f32x4 acc[4][4];
  const int tm = blockIdx.y, tn = blockIdx.x;
  gemm_nt_core(xbf, Wt, DIM, DIM, DIM, tm * 128, tn * 128, As, Bs, acc);

  const int tid = threadIdx.x, lane = tid & 63, wid = tid >> 6;
  const int wm = (wid & 1) << 6, wn = (wid >> 1) << 6;
  const float scale = 0.036084391824351615f;  // 1/sqrt(768)
#pragma unroll
  for (int i = 0; i < 4; ++i) {
#pragma unroll
    for (int j = 0; j < 4; ++j) {
      const int col  = tn * 128 + wn + j * 16 + (lane & 15);
      const int row0 = tm * 128 + wm + i * 16 + ((lane >> 4) << 2);
      const float bc = bias[col];
#pragma unroll
      for (int r = 0; r < 4; ++r) {
        const int row = row0 + r;              // global token index
        const float v = acc[i][j][r] + bc;
        if (col < 768) {
          qb[(size_t)row * DIM + col] = f2bf(v * scale);
        } else if (col < 1536) {
          kb[(size_t)row * DIM + (col - 768)] = f2bf(v);
        } else {
          const int b = row >> 12, n = row & 4095;
          vT[((size_t)b * DIM + (col - 1536)) * SEQ + n] = f2bf(v);
        }
      }
    }
  }
}

// ---- kernel 2: S[b] = q[b] @ k[b]^T (already scaled), bf16 out ----
__global__ __launch_bounds__(256) void k_scores(
    const unsigned short* __restrict__ qb, const unsigned short* __restrict__ kb,
    unsigned short* __restrict__ S)
{
  __shared__ unsigned short As[128 * 32];
  __shared__ unsigned short Bs[128 * 32];
  f32x4 acc[4][4];
  const int b = blockIdx.z;
  const unsigned short* A  = qb + (size_t)b * SEQ * DIM;
  const unsigned short* Bm = kb + (size_t)b * SEQ * DIM;
  unsigned short* Sb = S + (size_t)b * SEQ * SEQ;
  gemm_nt_core(A, Bm, DIM, DIM, DIM, blockIdx.y * 128, blockIdx.x * 128, As, Bs, acc);

  const int tid = threadIdx.x, lane = tid & 63, wid = tid >> 6;
  const int wm = (wid & 1) << 6, wn = (wid >> 1) << 6;
#pragma unroll
  for (int i = 0; i < 4; ++i)
#pragma unroll
    for (int j = 0; j < 4; ++j) {
      const int col  = blockIdx.x * 128 + wn + j * 16 + (lane & 15);
      const int row0 = blockIdx.y * 128 + wm + i * 16 + ((lane >> 4) << 2);
#pragma unroll
      for (int r = 0; r < 4; ++r)
        Sb[(size_t)(row0 + r) * SEQ + col] = f2bf(acc[i][j][r]);
    }
}

// ---- kernel 3: in-place row softmax over 4096 bf16, fp32 math ----
__global__ __launch_bounds__(256) void k_softmax(unsigned short* __restrict__ S)
{
  const size_t base = (size_t)blockIdx.x * SEQ;
  uint4* rp = (uint4*)(S + base);           // 512 chunks of 8 bf16
  const int t = threadIdx.x, lane = t & 63, wid = t >> 6;
  const uint4 cA = rp[t], cB = rp[t + 256];
  uint32_t wsv[8] = {cA.x, cA.y, cA.z, cA.w, cB.x, cB.y, cB.z, cB.w};
  float v[16];
#pragma unroll
  for (int i = 0; i < 8; ++i) {
    union { uint32_t u; float f; } lo, hi;
    lo.u = wsv[i] << 16; hi.u = wsv[i] & 0xFFFF0000u;
    v[2 * i] = lo.f; v[2 * i + 1] = hi.f;
  }
  float m = -1e30f;
#pragma unroll
  for (int i = 0; i < 16; ++i) m = fmaxf(m, v[i]);
#pragma unroll
  for (int off = 32; off > 0; off >>= 1) m = fmaxf(m, __shfl_down(m, off));
  __shared__ float redm[4], reds[4];
  if (lane == 0) redm[wid] = m;
  __syncthreads();
  m = fmaxf(fmaxf(redm[0], redm[1]), fmaxf(redm[2], redm[3]));
  float s = 0.f;
#pragma unroll
  for (int i = 0; i < 16; ++i) { v[i] = __expf(v[i] - m); s += v[i]; }
#pragma unroll
  for (int off = 32; off > 0; off >>= 1) s += __shfl_down(s, off);
  if (lane == 0) reds[wid] = s;
  __syncthreads();
  s = reds[0] + reds[1] + reds[2] + reds[3];
  const float inv = 1.0f / s;
  uint32_t o[8];
#pragma unroll
  for (int i = 0; i < 8; ++i)
    o[i] = (uint32_t)f2bf(v[2 * i] * inv) | ((uint32_t)f2bf(v[2 * i + 1] * inv) << 16);
  uint4 oA = {o[0], o[1], o[2], o[3]}, oB = {o[4], o[5], o[6], o[7]};
  rp[t] = oA; rp[t + 256] = oB;
}

// ---- kernel 4: out[b] = P[b] @ vT[b]^T, fp32 out ----
__global__ __launch_bounds__(256) void k_pv(
    const unsigned short* __restrict__ P, const unsigned short* __restrict__ vT,
    float* __restrict__ out)
{
  __shared__ unsigned short As[128 * 32];
  __shared__ unsigned short Bs[128 * 32];
  f32x4 acc[4][4];
  const int b = blockIdx.z;
  const unsigned short* A  = P + (size_t)b * SEQ * SEQ;
  const unsigned short* Bm = vT + (size_t)b * DIM * SEQ;
  float* ob = out + (size_t)b * SEQ * DIM;
  gemm_nt_core(A, Bm, SEQ, SEQ, SEQ, blockIdx.y * 128, blockIdx.x * 128, As, Bs, acc);

  const int tid = threadIdx.x, lane = tid & 63, wid = tid >> 6;
  const int wm = (wid & 1) << 6, wn = (wid >> 1) << 6;
#pragma unroll
  for (int i = 0; i < 4; ++i)
#pragma unroll
    for (int j = 0; j < 4; ++j) {
      const int col  = blockIdx.x * 128 + wn + j * 16 + (lane & 15);   // h
      const int row0 = blockIdx.y * 128 + wm + i * 16 + ((lane >> 4) << 2); // n
#pragma unroll
      for (int r = 0; r < 4; ++r)
        ob[(size_t)(row0 + r) * DIM + col] = acc[i][j][r];
    }
}

extern "C" void kernel_launch(void* const* d_in, const int* in_sizes, int n_in,
                              void* d_out, int out_size, void* d_ws, size_t ws_size,
                              hipStream_t stream) {
  const float* x    = (const float*)d_in[0];   // [4,4096,768]
  const float* W    = (const float*)d_in[1];   // [768,2304]
  const float* bias = (const float*)d_in[2];   // [2304]
  float* out = (float*)d_out;                  // [4,4096,768] fp32

  char* w = (char*)d_ws;
  unsigned short* x_bf = (unsigned short*)(w);             // 25,165,824 B
  unsigned short* Wt   = (unsigned short*)(w + 25165824);  //  3,538,944 B
  unsigned short* qb   = (unsigned short*)(w + 28704768);  // 25,165,824 B
  unsigned short* kb   = (unsigned short*)(w + 53870592);  // 25,165,824 B
  unsigned short* vT   = (unsigned short*)(w + 79036416);  // 25,165,824 B
  unsigned short* S    = (unsigned short*)(w + 104202240); // 134,217,728 B (S then P in-place)

  k_cvt      <<<12288, 256, 0, stream>>>(x, x_bf);                  // 16384*768/4
  k_transpose<<<dim3(72, 24), 256, 0, stream>>>(W, Wt);
  k_qkv      <<<dim3(18, 128), 256, 0, stream>>>(x_bf, Wt, bias, qb, kb, vT);
  k_scores   <<<dim3(32, 32, 4), 256, 0, stream>>>(qb, kb, S);
  k_softmax  <<<16384, 256, 0, stream>>>(S);
  k_pv       <<<dim3(6, 32, 4), 256, 0, stream>>>(S, vT, out);
}

// Round 2
// 527.953 us; speedup vs baseline: 1.1428x; 1.1428x over previous
//
#include <hip/hip_runtime.h>
#include <stdint.h>

typedef __attribute__((ext_vector_type(8))) short short8;
typedef __attribute__((ext_vector_type(4))) float f32x4;

#define DIM 768
#define H3 2304
#define SEQ 4096
#define NTOK 16384

__device__ __forceinline__ unsigned short f2bf(float f) {
  union { float f; uint32_t u; } c; c.f = f;
  uint32_t u = c.u;
  u += 0x7FFFu + ((u >> 16) & 1u);   // RNE; inputs are finite
  return (unsigned short)(u >> 16);
}

__device__ __forceinline__ void async_cp16(const void* g, void* l) {
  // global -> LDS direct, 16B per lane. LDS dest must be waveBase + lane*16 (it is).
  __builtin_amdgcn_global_load_lds(
      (__attribute__((address_space(1))) void*)(void*)g,
      (__attribute__((address_space(3))) void*)l, 16, 0, 0);
}

// NT GEMM core (BK=32): C[128x128] = A[128xK] * B[128xK]^T, bf16 in, fp32 acc.
// 256 threads = 4 waves, each wave 64x64 (4x4 of 16x16x32 MFMA).
__device__ __forceinline__ void gemm_nt_core(
    const unsigned short* __restrict__ A, const unsigned short* __restrict__ B,
    int K, int ldA, int ldB, int rowA0, int rowB0,
    unsigned short* As, unsigned short* Bs, f32x4 acc[4][4])
{
  const int tid  = threadIdx.x;
  const int lane = tid & 63;
  const int wid  = tid >> 6;
  const int wm   = (wid & 1) << 6;
  const int wn   = (wid >> 1) << 6;

#pragma unroll
  for (int i = 0; i < 4; ++i)
#pragma unroll
    for (int j = 0; j < 4; ++j)
      acc[i][j] = (f32x4){0.f, 0.f, 0.f, 0.f};

  const int c0 = tid, c1 = tid + 256;
  const int r0 = c0 >> 2, cc0 = (c0 & 3) << 3;
  const int r1 = c1 >> 2, cc1 = (c1 & 3) << 3;
  const unsigned short* ga0 = A + (size_t)(rowA0 + r0) * ldA + cc0;
  const unsigned short* ga1 = A + (size_t)(rowA0 + r1) * ldA + cc1;
  const unsigned short* gb0 = B + (size_t)(rowB0 + r0) * ldB + cc0;
  const unsigned short* gb1 = B + (size_t)(rowB0 + r1) * ldB + cc1;

  const int lr = lane & 15;
  const int kq = (lane >> 4) << 3;

  for (int k0 = 0; k0 < K; k0 += 32) {
    async_cp16(ga0 + k0, As + c0 * 8);
    async_cp16(ga1 + k0, As + c1 * 8);
    async_cp16(gb0 + k0, Bs + c0 * 8);
    async_cp16(gb1 + k0, Bs + c1 * 8);
    __syncthreads();

    short8 af[4], bfr[4];
#pragma unroll
    for (int i = 0; i < 4; ++i)
      af[i] = *(const short8*)(As + (wm + i * 16 + lr) * 32 + kq);
#pragma unroll
    for (int j = 0; j < 4; ++j)
      bfr[j] = *(const short8*)(Bs + (wn + j * 16 + lr) * 32 + kq);
#pragma unroll
    for (int i = 0; i < 4; ++i)
#pragma unroll
      for (int j = 0; j < 4; ++j)
        acc[i][j] = __builtin_amdgcn_mfma_f32_16x16x32_bf16(af[i], bfr[j], acc[i][j], 0, 0, 0);
    __syncthreads();
  }
}

// ---- kernel 0a: fp32 -> bf16 bulk convert (x) ----
__global__ __launch_bounds__(256) void k_cvt(const float* __restrict__ in,
                                             unsigned short* __restrict__ o) {
  int i = blockIdx.x * 256 + threadIdx.x;
  float4 f = ((const float4*)in)[i];
  ushort4 u;
  u.x = f2bf(f.x); u.y = f2bf(f.y); u.z = f2bf(f.z); u.w = f2bf(f.w);
  ((ushort4*)o)[i] = u;
}

// ---- kernel 0b: W [768,2304] fp32 -> Wt [2304,768] bf16 ----
__global__ __launch_bounds__(256) void k_transpose(const float* __restrict__ W,
                                                   unsigned short* __restrict__ Wt) {
  __shared__ float tile[32][33];
  const int bc = blockIdx.x * 32;
  const int br = blockIdx.y * 32;
  const int tx = threadIdx.x & 31, ty = threadIdx.x >> 5;
#pragma unroll
  for (int i = 0; i < 32; i += 8)
    tile[ty + i][tx] = W[(size_t)(br + ty + i) * H3 + bc + tx];
  __syncthreads();
#pragma unroll
  for (int i = 0; i < 32; i += 8)
    Wt[(size_t)(bc + ty + i) * DIM + br + tx] = f2bf(tile[tx][ty + i]);
}

// ---- kernel 1: qkv = x @ Wt^T + b ----
// flat grid 2304; XCD swizzle: all 18 col-tiles of one x row-strip on one XCD.
__global__ __launch_bounds__(256) void k_qkv(
    const unsigned short* __restrict__ xbf, const unsigned short* __restrict__ Wt,
    const float* __restrict__ bias,
    unsigned short* __restrict__ qb, unsigned short* __restrict__ kb,
    unsigned short* __restrict__ vT)
{
  __shared__ unsigned short As[128 * 32];
  __shared__ unsigned short Bs[128 * 32];
  f32x4 acc[4][4];
  const int g = blockIdx.x;
  const int xcd = g & 7, slot = g >> 3;        // slot in [0,288)
  const int tn = slot % 18, grp = slot / 18;   // grp in [0,16)
  const int tm = xcd + 8 * grp;                // row-strip in [0,128)
  gemm_nt_core(xbf, Wt, DIM, DIM, DIM, tm * 128, tn * 128, As, Bs, acc);

  const int tid = threadIdx.x, lane = tid & 63, wid = tid >> 6;
  const int wm = (wid & 1) << 6, wn = (wid >> 1) << 6;
  const float scale = 0.036084391824351615f;  // 1/sqrt(768)
#pragma unroll
  for (int i = 0; i < 4; ++i) {
#pragma unroll
    for (int j = 0; j < 4; ++j) {
      const int col  = tn * 128 + wn + j * 16 + (lane & 15);
      const int row0 = tm * 128 + wm + i * 16 + ((lane >> 4) << 2);
      const float bc = bias[col];
#pragma unroll
      for (int r = 0; r < 4; ++r) {
        const int row = row0 + r;
        const float v = acc[i][j][r] + bc;
        if (col < 768) {
          qb[(size_t)row * DIM + col] = f2bf(v * scale);
        } else if (col < 1536) {
          kb[(size_t)row * DIM + (col - 768)] = f2bf(v);
        } else {
          const int b = row >> 12, n = row & 4095;
          vT[((size_t)b * DIM + (col - 1536)) * SEQ + n] = f2bf(v);
        }
      }
    }
  }
}

// ---- kernel 2: S[b] = q[b] @ k[b]^T, bf16 out ----
// flat grid 4096; XCD swizzle: 32 col-tiles of one q row-strip on one XCD.
__global__ __launch_bounds__(256) void k_scores(
    const unsigned short* __restrict__ qb, const unsigned short* __restrict__ kb,
    unsigned short* __restrict__ S)
{
  __shared__ unsigned short As[128 * 32];
  __shared__ unsigned short Bs[128 * 32];
  f32x4 acc[4][4];
  const int g = blockIdx.x;
  const int xcd = g & 7, slot = g >> 3;        // slot in [0,512)
  const int tn = slot & 31, grp = slot >> 5;   // grp in [0,16)
  const int s  = xcd + 8 * grp;                // strip in [0,128)
  const int ty = s & 31, b = s >> 5;
  const unsigned short* A  = qb + (size_t)b * SEQ * DIM;
  const unsigned short* Bm = kb + (size_t)b * SEQ * DIM;
  unsigned short* Sb = S + (size_t)b * SEQ * SEQ;
  gemm_nt_core(A, Bm, DIM, DIM, DIM, ty * 128, tn * 128, As, Bs, acc);

  const int tid = threadIdx.x, lane = tid & 63, wid = tid >> 6;
  const int wm = (wid & 1) << 6, wn = (wid >> 1) << 6;
#pragma unroll
  for (int i = 0; i < 4; ++i)
#pragma unroll
    for (int j = 0; j < 4; ++j) {
      const int col  = tn * 128 + wn + j * 16 + (lane & 15);
      const int row0 = ty * 128 + wm + i * 16 + ((lane >> 4) << 2);
#pragma unroll
      for (int r = 0; r < 4; ++r)
        Sb[(size_t)(row0 + r) * SEQ + col] = f2bf(acc[i][j][r]);
    }
}

// ---- kernel 3: in-place row softmax over 4096 bf16 ----
__global__ __launch_bounds__(256) void k_softmax(unsigned short* __restrict__ S)
{
  const size_t base = (size_t)blockIdx.x * SEQ;
  uint4* rp = (uint4*)(S + base);
  const int t = threadIdx.x, lane = t & 63, wid = t >> 6;
  const uint4 cA = rp[t], cB = rp[t + 256];
  uint32_t wsv[8] = {cA.x, cA.y, cA.z, cA.w, cB.x, cB.y, cB.z, cB.w};
  float v[16];
#pragma unroll
  for (int i = 0; i < 8; ++i) {
    union { uint32_t u; float f; } lo, hi;
    lo.u = wsv[i] << 16; hi.u = wsv[i] & 0xFFFF0000u;
    v[2 * i] = lo.f; v[2 * i + 1] = hi.f;
  }
  float m = -1e30f;
#pragma unroll
  for (int i = 0; i < 16; ++i) m = fmaxf(m, v[i]);
#pragma unroll
  for (int off = 32; off > 0; off >>= 1) m = fmaxf(m, __shfl_down(m, off));
  __shared__ float redm[4], reds[4];
  if (lane == 0) redm[wid] = m;
  __syncthreads();
  m = fmaxf(fmaxf(redm[0], redm[1]), fmaxf(redm[2], redm[3]));
  float s = 0.f;
#pragma unroll
  for (int i = 0; i < 16; ++i) { v[i] = __expf(v[i] - m); s += v[i]; }
#pragma unroll
  for (int off = 32; off > 0; off >>= 1) s += __shfl_down(s, off);
  if (lane == 0) reds[wid] = s;
  __syncthreads();
  s = reds[0] + reds[1] + reds[2] + reds[3];
  const float inv = 1.0f / s;
  uint32_t o[8];
#pragma unroll
  for (int i = 0; i < 8; ++i)
    o[i] = (uint32_t)f2bf(v[2 * i] * inv) | ((uint32_t)f2bf(v[2 * i + 1] * inv) << 16);
  uint4 oA = {o[0], o[1], o[2], o[3]}, oB = {o[4], o[5], o[6], o[7]};
  rp[t] = oA; rp[t + 256] = oB;
}

// ---- kernel 4: out[b] = P[b] @ vT[b]^T, fp32 out ----
// BK=64 (32 MFMA per barrier), XOR-swizzled LDS (global-source side), XCD swizzle.
__global__ __launch_bounds__(256) void k_pv(
    const unsigned short* __restrict__ P, const unsigned short* __restrict__ vT,
    float* __restrict__ out)
{
  __shared__ unsigned short As[128 * 64];
  __shared__ unsigned short Bs[128 * 64];

  const int g = blockIdx.x;                    // flat grid 768
  const int xcd = g & 7, slot = g >> 3;        // slot in [0,96)
  const int tn = slot % 6, grp = slot / 6;     // grp in [0,16)
  const int s  = xcd + 8 * grp;                // strip in [0,128)
  const int ty = s & 31, b = s >> 5;

  const unsigned short* A  = P  + (size_t)b * SEQ * SEQ + (size_t)(ty * 128) * SEQ;
  const unsigned short* Bm = vT + (size_t)b * DIM * SEQ + (size_t)(tn * 128) * SEQ;
  float* ob = out + (size_t)b * SEQ * DIM;

  const int tid = threadIdx.x, lane = tid & 63, wid = tid >> 6;
  const int wm = (wid & 1) << 6, wn = (wid >> 1) << 6;
  const int lr = lane & 15, q = lane >> 4;

  f32x4 acc[4][4];
#pragma unroll
  for (int i = 0; i < 4; ++i)
#pragma unroll
    for (int j = 0; j < 4; ++j)
      acc[i][j] = (f32x4){0.f, 0.f, 0.f, 0.f};

  // staging: 128 rows x 64 cols = 1024 chunks of 16B; 4 per thread per operand.
  // LDS slot c holds source chunk (row=c>>3, kChunk=(c&7)^(row&7)).
  const unsigned short* gA[4];
  const unsigned short* gB[4];
#pragma unroll
  for (int t = 0; t < 4; ++t) {
    const int c = tid + 256 * t;
    const int row = c >> 3, sc = c & 7;
    const int col8 = ((sc ^ (row & 7)) << 3);
    gA[t] = A  + (size_t)row * SEQ + col8;
    gB[t] = Bm + (size_t)row * SEQ + col8;
  }

  for (int k0 = 0; k0 < SEQ; k0 += 64) {
#pragma unroll
    for (int t = 0; t < 4; ++t)
      async_cp16(gA[t] + k0, As + (tid + 256 * t) * 8);
#pragma unroll
    for (int t = 0; t < 4; ++t)
      async_cp16(gB[t] + k0, Bs + (tid + 256 * t) * 8);
    __syncthreads();

    short8 af[4][2], bfr[4][2];
#pragma unroll
    for (int i = 0; i < 4; ++i) {
      const int ra = wm + i * 16 + lr;
#pragma unroll
      for (int s2 = 0; s2 < 2; ++s2)
        af[i][s2] = *(const short8*)(As + ra * 64 + (((s2 * 4 + q) ^ (ra & 7)) << 3));
    }
#pragma unroll
    for (int j = 0; j < 4; ++j) {
      const int rb = wn + j * 16 + lr;
#pragma unroll
      for (int s2 = 0; s2 < 2; ++s2)
        bfr[j][s2] = *(const short8*)(Bs + rb * 64 + (((s2 * 4 + q) ^ (rb & 7)) << 3));
    }
#pragma unroll
    for (int s2 = 0; s2 < 2; ++s2)
#pragma unroll
      for (int i = 0; i < 4; ++i)
#pragma unroll
        for (int j = 0; j < 4; ++j)
          acc[i][j] = __builtin_amdgcn_mfma_f32_16x16x32_bf16(af[i][s2], bfr[j][s2], acc[i][j], 0, 0, 0);
    __syncthreads();
  }

#pragma unroll
  for (int i = 0; i < 4; ++i)
#pragma unroll
    for (int j = 0; j < 4; ++j) {
      const int col  = tn * 128 + wn + j * 16 + (lane & 15);
      const int row0 = ty * 128 + wm + i * 16 + ((lane >> 4) << 2);
#pragma unroll
      for (int r = 0; r < 4; ++r)
        ob[(size_t)(row0 + r) * DIM + col] = acc[i][j][r];
    }
}

extern "C" void kernel_launch(void* const* d_in, const int* in_sizes, int n_in,
                              void* d_out, int out_size, void* d_ws, size_t ws_size,
                              hipStream_t stream) {
  const float* x    = (const float*)d_in[0];
  const float* W    = (const float*)d_in[1];
  const float* bias = (const float*)d_in[2];
  float* out = (float*)d_out;

  char* w = (char*)d_ws;
  unsigned short* x_bf = (unsigned short*)(w);
  unsigned short* Wt   = (unsigned short*)(w + 25165824);
  unsigned short* qb   = (unsigned short*)(w + 28704768);
  unsigned short* kb   = (unsigned short*)(w + 53870592);
  unsigned short* vT   = (unsigned short*)(w + 79036416);
  unsigned short* S    = (unsigned short*)(w + 104202240);

  k_cvt      <<<12288, 256, 0, stream>>>(x, x_bf);
  k_transpose<<<dim3(72, 24), 256, 0, stream>>>(W, Wt);
  k_qkv      <<<2304, 256, 0, stream>>>(x_bf, Wt, bias, qb, kb, vT);
  k_scores   <<<4096, 256, 0, stream>>>(qb, kb, S);
  k_softmax  <<<16384, 256, 0, stream>>>(S);
  k_pv       <<<768, 256, 0, stream>>>(S, vT, out);
}

// Round 3
// 512.044 us; speedup vs baseline: 1.1783x; 1.0311x over previous
//
#include <hip/hip_runtime.h>
#include <stdint.h>

typedef __attribute__((ext_vector_type(8))) short short8;
typedef __attribute__((ext_vector_type(4))) float f32x4;

#define DIM 768
#define H3 2304
#define SEQ 4096
#define NTOK 16384

__device__ __forceinline__ unsigned short f2bf(float f) {
  union { float f; uint32_t u; } c; c.f = f;
  uint32_t u = c.u;
  u += 0x7FFFu + ((u >> 16) & 1u);   // RNE; inputs are finite
  return (unsigned short)(u >> 16);
}

__device__ __forceinline__ void async_cp16(const void* g, void* l) {
  // global -> LDS direct, 16B per lane. LDS dest must be waveBase + lane*16 (it is).
  __builtin_amdgcn_global_load_lds(
      (__attribute__((address_space(1))) void*)(void*)g,
      (__attribute__((address_space(3))) void*)l, 16, 0, 0);
}

// ---- shared NT GEMM core, BK=64, XOR-swizzled LDS chunks ----
// C[128x128] = A[128xK] * B[128xK]^T, bf16 in, fp32 acc.
// A/B point at the 128-row strip base. 256 threads = 4 waves, 64x64 per wave
// (4x4 of 16x16x32 MFMA), 32 MFMA per barrier pair.
// LDS slot c holds source chunk (row=c>>3, kChunk=(c&7)^(row&7)) so fragment
// ds_read_b128s land on distinct bank groups while the global_load_lds dest
// stays lane-contiguous (HW requirement).
__device__ __forceinline__ void gemm_nt64(
    const unsigned short* __restrict__ A, const unsigned short* __restrict__ B,
    int K, int ldA, int ldB,
    unsigned short* As, unsigned short* Bs, f32x4 acc[4][4])
{
  const int tid = threadIdx.x, lane = tid & 63, wid = tid >> 6;
  const int wm = (wid & 1) << 6, wn = (wid >> 1) << 6;
  const int lr = lane & 15, q = lane >> 4;

#pragma unroll
  for (int i = 0; i < 4; ++i)
#pragma unroll
    for (int j = 0; j < 4; ++j)
      acc[i][j] = (f32x4){0.f, 0.f, 0.f, 0.f};

  // staging: 128 rows x 64 cols = 1024 chunks of 16B; 4 per thread per operand
  const unsigned short* gA[4];
  const unsigned short* gB[4];
#pragma unroll
  for (int t = 0; t < 4; ++t) {
    const int c = tid + 256 * t;
    const int row = c >> 3, sc = c & 7;
    const int col8 = ((sc ^ (row & 7)) << 3);
    gA[t] = A + (size_t)row * ldA + col8;
    gB[t] = B + (size_t)row * ldB + col8;
  }

  for (int k0 = 0; k0 < K; k0 += 64) {
#pragma unroll
    for (int t = 0; t < 4; ++t)
      async_cp16(gA[t] + k0, As + (tid + 256 * t) * 8);
#pragma unroll
    for (int t = 0; t < 4; ++t)
      async_cp16(gB[t] + k0, Bs + (tid + 256 * t) * 8);
    __syncthreads();

    short8 af[4][2], bfr[4][2];
#pragma unroll
    for (int i = 0; i < 4; ++i) {
      const int ra = wm + i * 16 + lr;
#pragma unroll
      for (int s2 = 0; s2 < 2; ++s2)
        af[i][s2] = *(const short8*)(As + ra * 64 + (((s2 * 4 + q) ^ (ra & 7)) << 3));
    }
#pragma unroll
    for (int j = 0; j < 4; ++j) {
      const int rb = wn + j * 16 + lr;
#pragma unroll
      for (int s2 = 0; s2 < 2; ++s2)
        bfr[j][s2] = *(const short8*)(Bs + rb * 64 + (((s2 * 4 + q) ^ (rb & 7)) << 3));
    }
#pragma unroll
    for (int s2 = 0; s2 < 2; ++s2)
#pragma unroll
      for (int i = 0; i < 4; ++i)
#pragma unroll
        for (int j = 0; j < 4; ++j)
          acc[i][j] = __builtin_amdgcn_mfma_f32_16x16x32_bf16(af[i][s2], bfr[j][s2], acc[i][j], 0, 0, 0);
    __syncthreads();
  }
}

// ---- kernel 0a: fp32 -> bf16 bulk convert (x) ----
__global__ __launch_bounds__(256) void k_cvt(const float* __restrict__ in,
                                             unsigned short* __restrict__ o) {
  int i = blockIdx.x * 256 + threadIdx.x;
  float4 f = ((const float4*)in)[i];
  ushort4 u;
  u.x = f2bf(f.x); u.y = f2bf(f.y); u.z = f2bf(f.z); u.w = f2bf(f.w);
  ((ushort4*)o)[i] = u;
}

// ---- kernel 0b: W [768,2304] fp32 -> Wt [2304,768] bf16 ----
__global__ __launch_bounds__(256) void k_transpose(const float* __restrict__ W,
                                                   unsigned short* __restrict__ Wt) {
  __shared__ float tile[32][33];
  const int bc = blockIdx.x * 32;
  const int br = blockIdx.y * 32;
  const int tx = threadIdx.x & 31, ty = threadIdx.x >> 5;
#pragma unroll
  for (int i = 0; i < 32; i += 8)
    tile[ty + i][tx] = W[(size_t)(br + ty + i) * H3 + bc + tx];
  __syncthreads();
#pragma unroll
  for (int i = 0; i < 32; i += 8)
    Wt[(size_t)(bc + ty + i) * DIM + br + tx] = f2bf(tile[tx][ty + i]);
}

// ---- kernel 1: qkv = x @ Wt^T + b ; q scaled, k plain, v transposed ----
__global__ __launch_bounds__(256) void k_qkv(
    const unsigned short* __restrict__ xbf, const unsigned short* __restrict__ Wt,
    const float* __restrict__ bias,
    unsigned short* __restrict__ qb, unsigned short* __restrict__ kb,
    unsigned short* __restrict__ vT)
{
  __shared__ unsigned short As[128 * 64];
  __shared__ unsigned short Bs[128 * 64];
  f32x4 acc[4][4];
  const int g = blockIdx.x;
  const int xcd = g & 7, slot = g >> 3;        // slot in [0,288)
  const int tn = slot % 18, grp = slot / 18;   // grp in [0,16)
  const int tm = xcd + 8 * grp;                // row-strip in [0,128)
  gemm_nt64(xbf + (size_t)(tm * 128) * DIM, Wt + (size_t)(tn * 128) * DIM,
            DIM, DIM, DIM, As, Bs, acc);

  const int tid = threadIdx.x, lane = tid & 63, wid = tid >> 6;
  const int wm = (wid & 1) << 6, wn = (wid >> 1) << 6;
  const float scale = 0.036084391824351615f;  // 1/sqrt(768)
#pragma unroll
  for (int i = 0; i < 4; ++i) {
#pragma unroll
    for (int j = 0; j < 4; ++j) {
      const int col  = tn * 128 + wn + j * 16 + (lane & 15);
      const int row0 = tm * 128 + wm + i * 16 + ((lane >> 4) << 2);
      const float bc = bias[col];
#pragma unroll
      for (int r = 0; r < 4; ++r) {
        const int row = row0 + r;
        const float v = acc[i][j][r] + bc;
        if (col < 768) {
          qb[(size_t)row * DIM + col] = f2bf(v * scale);
        } else if (col < 1536) {
          kb[(size_t)row * DIM + (col - 768)] = f2bf(v);
        } else {
          const int b = row >> 12, n = row & 4095;
          vT[((size_t)b * DIM + (col - 1536)) * SEQ + n] = f2bf(v);
        }
      }
    }
  }
}

// ---- kernel 2: S[b] = q[b] @ k[b]^T (q pre-scaled), bf16 out ----
__global__ __launch_bounds__(256) void k_scores(
    const unsigned short* __restrict__ qb, const unsigned short* __restrict__ kb,
    unsigned short* __restrict__ S)
{
  __shared__ unsigned short As[128 * 64];
  __shared__ unsigned short Bs[128 * 64];
  f32x4 acc[4][4];
  const int g = blockIdx.x;
  const int xcd = g & 7, slot = g >> 3;        // slot in [0,512)
  const int tn = slot & 31, grp = slot >> 5;   // grp in [0,16)
  const int s  = xcd + 8 * grp;                // strip in [0,128)
  const int ty = s & 31, b = s >> 5;
  const unsigned short* A  = qb + (size_t)b * SEQ * DIM + (size_t)(ty * 128) * DIM;
  const unsigned short* Bm = kb + (size_t)b * SEQ * DIM + (size_t)(tn * 128) * DIM;
  unsigned short* Sb = S + (size_t)b * SEQ * SEQ;
  gemm_nt64(A, Bm, DIM, DIM, DIM, As, Bs, acc);

  const int tid = threadIdx.x, lane = tid & 63, wid = tid >> 6;
  const int wm = (wid & 1) << 6, wn = (wid >> 1) << 6;
#pragma unroll
  for (int i = 0; i < 4; ++i)
#pragma unroll
    for (int j = 0; j < 4; ++j) {
      const int col  = tn * 128 + wn + j * 16 + (lane & 15);
      const int row0 = ty * 128 + wm + i * 16 + ((lane >> 4) << 2);
#pragma unroll
      for (int r = 0; r < 4; ++r)
        Sb[(size_t)(row0 + r) * SEQ + col] = f2bf(acc[i][j][r]);
    }
}

// ---- kernel 3: in-place row softmax over 4096 bf16 ----
__global__ __launch_bounds__(256) void k_softmax(unsigned short* __restrict__ S)
{
  const size_t base = (size_t)blockIdx.x * SEQ;
  uint4* rp = (uint4*)(S + base);
  const int t = threadIdx.x, lane = t & 63, wid = t >> 6;
  const uint4 cA = rp[t], cB = rp[t + 256];
  uint32_t wsv[8] = {cA.x, cA.y, cA.z, cA.w, cB.x, cB.y, cB.z, cB.w};
  float v[16];
#pragma unroll
  for (int i = 0; i < 8; ++i) {
    union { uint32_t u; float f; } lo, hi;
    lo.u = wsv[i] << 16; hi.u = wsv[i] & 0xFFFF0000u;
    v[2 * i] = lo.f; v[2 * i + 1] = hi.f;
  }
  float m = -1e30f;
#pragma unroll
  for (int i = 0; i < 16; ++i) m = fmaxf(m, v[i]);
#pragma unroll
  for (int off = 32; off > 0; off >>= 1) m = fmaxf(m, __shfl_down(m, off));
  __shared__ float redm[4], reds[4];
  if (lane == 0) redm[wid] = m;
  __syncthreads();
  m = fmaxf(fmaxf(redm[0], redm[1]), fmaxf(redm[2], redm[3]));
  float s = 0.f;
#pragma unroll
  for (int i = 0; i < 16; ++i) { v[i] = __expf(v[i] - m); s += v[i]; }
#pragma unroll
  for (int off = 32; off > 0; off >>= 1) s += __shfl_down(s, off);
  if (lane == 0) reds[wid] = s;
  __syncthreads();
  s = reds[0] + reds[1] + reds[2] + reds[3];
  const float inv = 1.0f / s;
  uint32_t o[8];
#pragma unroll
  for (int i = 0; i < 8; ++i)
    o[i] = (uint32_t)f2bf(v[2 * i] * inv) | ((uint32_t)f2bf(v[2 * i + 1] * inv) << 16);
  uint4 oA = {o[0], o[1], o[2], o[3]}, oB = {o[4], o[5], o[6], o[7]};
  rp[t] = oA; rp[t + 256] = oB;
}

// ---- kernel 4: out[b] = P[b] @ vT[b]^T, fp32 out ----
__global__ __launch_bounds__(256) void k_pv(
    const unsigned short* __restrict__ P, const unsigned short* __restrict__ vT,
    float* __restrict__ out)
{
  __shared__ unsigned short As[128 * 64];
  __shared__ unsigned short Bs[128 * 64];
  f32x4 acc[4][4];
  const int g = blockIdx.x;                    // flat grid 768
  const int xcd = g & 7, slot = g >> 3;        // slot in [0,96)
  const int tn = slot % 6, grp = slot / 6;     // grp in [0,16)
  const int s  = xcd + 8 * grp;                // strip in [0,128)
  const int ty = s & 31, b = s >> 5;

  const unsigned short* A  = P  + (size_t)b * SEQ * SEQ + (size_t)(ty * 128) * SEQ;
  const unsigned short* Bm = vT + (size_t)b * DIM * SEQ + (size_t)(tn * 128) * SEQ;
  float* ob = out + (size_t)b * SEQ * DIM;
  gemm_nt64(A, Bm, SEQ, SEQ, SEQ, As, Bs, acc);

  const int tid = threadIdx.x, lane = tid & 63, wid = tid >> 6;
  const int wm = (wid & 1) << 6, wn = (wid >> 1) << 6;
#pragma unroll
  for (int i = 0; i < 4; ++i)
#pragma unroll
    for (int j = 0; j < 4; ++j) {
      const int col  = tn * 128 + wn + j * 16 + (lane & 15);
      const int row0 = ty * 128 + wm + i * 16 + ((lane >> 4) << 2);
#pragma unroll
      for (int r = 0; r < 4; ++r)
        ob[(size_t)(row0 + r) * DIM + col] = acc[i][j][r];
    }
}

extern "C" void kernel_launch(void* const* d_in, const int* in_sizes, int n_in,
                              void* d_out, int out_size, void* d_ws, size_t ws_size,
                              hipStream_t stream) {
  const float* x    = (const float*)d_in[0];
  const float* W    = (const float*)d_in[1];
  const float* bias = (const float*)d_in[2];
  float* out = (float*)d_out;

  char* w = (char*)d_ws;
  unsigned short* x_bf = (unsigned short*)(w);
  unsigned short* Wt   = (unsigned short*)(w + 25165824);
  unsigned short* qb   = (unsigned short*)(w + 28704768);
  unsigned short* kb   = (unsigned short*)(w + 53870592);
  unsigned short* vT   = (unsigned short*)(w + 79036416);
  unsigned short* S    = (unsigned short*)(w + 104202240);

  k_cvt      <<<12288, 256, 0, stream>>>(x, x_bf);
  k_transpose<<<dim3(72, 24), 256, 0, stream>>>(W, Wt);
  k_qkv      <<<2304, 256, 0, stream>>>(x_bf, Wt, bias, qb, kb, vT);
  k_scores   <<<4096, 256, 0, stream>>>(qb, kb, S);
  k_softmax  <<<16384, 256, 0, stream>>>(S);
  k_pv       <<<768, 256, 0, stream>>>(S, vT, out);
}